// Round 1
// baseline (31.834 us; speedup 1.0000x reference)
//
#include <hip/hip_runtime.h>

#define KS 16
#define HID 64
#define OC 8
#define LEN 8192
#define OUT_LEN (LEN - KS + 1)   // 8177
#define BATCH 64
#define TPB 256
#define BLOCKS_PER_BATCH ((OUT_LEN + TPB - 1) / TPB)  // 32

__global__ __launch_bounds__(TPB, 4) void conv_mlp_kernel(
    const float* __restrict__ x, const float* __restrict__ W1,
    const float* __restrict__ b1, const float* __restrict__ W2,
    const float* __restrict__ b2, float* __restrict__ out)
{
    const int b    = blockIdx.x / BLOCKS_PER_BATCH;
    const int pblk = blockIdx.x % BLOCKS_PER_BATCH;
    const int p    = pblk * TPB + threadIdx.x;
    if (p >= OUT_LEN) return;

    const float* xb = x + (size_t)b * LEN;

    // 16 window values; lane-consecutive addresses -> coalesced, L1 reuse.
    float xv[KS];
#pragma unroll
    for (int k = 0; k < KS; ++k) xv[k] = xb[p + k];

    // Layer 1: h[j] = b1[j] + sum_k xv[k] * W1[k][j]
    // k-outer / j-inner: 64 independent accumulator chains -> max ILP.
    // W1 index is wave-uniform -> scalar loads feed SGPR-operand v_fma.
    float h[HID];
#pragma unroll
    for (int j = 0; j < HID; ++j) h[j] = b1[j];
#pragma unroll
    for (int k = 0; k < KS; ++k) {
        const float xk = xv[k];
#pragma unroll
        for (int j = 0; j < HID; ++j)
            h[j] = fmaf(xk, W1[k * HID + j], h[j]);
    }

    // Layer 2 fused with tanh: y[c] = b2[c] + sum_j tanh(h[j]) * W2[j][c]
    float y[OC];
#pragma unroll
    for (int c = 0; c < OC; ++c) y[c] = b2[c];
#pragma unroll
    for (int j = 0; j < HID; ++j) {
        // tanh(v) = 1 - 2/(exp2(v * 2*log2(e)) + 1); saturates to +-1 correctly.
        float e = __builtin_amdgcn_exp2f(h[j] * 2.885390081777927f);
        float t = fmaf(-2.0f, __builtin_amdgcn_rcpf(e + 1.0f), 1.0f);
#pragma unroll
        for (int c = 0; c < OC; ++c)
            y[c] = fmaf(t, W2[j * OC + c], y[c]);
    }

    // out flat layout == reference flat layout: (b*OUT_LEN + o)*8 + c
    float4* o4 = reinterpret_cast<float4*>(out + ((size_t)b * OUT_LEN + p) * OC);
    o4[0] = make_float4(y[0], y[1], y[2], y[3]);
    o4[1] = make_float4(y[4], y[5], y[6], y[7]);
}

extern "C" void kernel_launch(void* const* d_in, const int* in_sizes, int n_in,
                              void* d_out, int out_size, void* d_ws, size_t ws_size,
                              hipStream_t stream) {
    const float* x  = (const float*)d_in[0];
    const float* W1 = (const float*)d_in[1];
    const float* b1 = (const float*)d_in[2];
    const float* W2 = (const float*)d_in[3];
    const float* b2 = (const float*)d_in[4];
    float* out = (float*)d_out;

    dim3 grid(BATCH * BLOCKS_PER_BATCH);
    conv_mlp_kernel<<<grid, TPB, 0, stream>>>(x, W1, b1, W2, b2, out);
}

// Round 2
// 21.673 us; speedup vs baseline: 1.4688x; 1.4688x over previous
//
#include <hip/hip_runtime.h>

#define KS 16
#define HID 64
#define OC 8
#define LEN 8192
#define OUT_LEN (LEN - KS + 1)   // 8177
#define BATCH 64
#define TPW 8                     // tiles (of 16 positions) per wave
#define TILES_PER_BATCH 512       // ceil(8177/16)

typedef __attribute__((ext_vector_type(8))) short short8;   // 8 bf16
typedef __attribute__((ext_vector_type(4))) float f32x4;

// round-to-nearest-even f32 -> bf16 (as raw short)
static __device__ inline short bf16_of(float f) {
    union { float f; unsigned u; } v; v.f = f;
    unsigned r = (v.u + 0x7fffu + ((v.u >> 16) & 1u)) >> 16;
    return (short)r;
}

__global__ __launch_bounds__(256, 4) void conv_mlp_mfma(
    const float* __restrict__ x, const float* __restrict__ W1,
    const float* __restrict__ b1, const float* __restrict__ W2,
    const float* __restrict__ b2, float* __restrict__ out)
{
    const int lane = threadIdx.x & 63;
    const int wave = threadIdx.x >> 6;
    const int col  = lane & 15;   // position within tile (B/D), c (A2), j-row mm (A1)
    const int g    = lane >> 4;   // 16-lane group

    const int batch = blockIdx.x >> 4;      // 16 blocks (strips) per batch
    const int strip = blockIdx.x & 15;
    const int tile0 = strip * 32 + wave * TPW;   // 4 waves x 8 tiles = 32-tile strip

    // ---- A1 fragments: W1^T j-tiles (j = 16T + col), k-slot (g,e) -> k = 8g+e.
    //      k >= 16 zero-padded; slot (g=2,e=0) carries b1 (pairs with B1 slot = 1.0).
    short8 a1[4];
#pragma unroll
    for (int T = 0; T < 4; ++T) {
#pragma unroll
        for (int e = 0; e < 8; ++e) {
            float v = 0.0f;
            if (g < 2)                 v = W1[(8 * g + e) * HID + 16 * T + col];
            else if (g == 2 && e == 0) v = b1[16 * T + col];
            a1[T][e] = bf16_of(v);
        }
    }

    // ---- A2 fragments: W2^T, slot (g,e) of K-tile t -> j = 32t + 16(e>>2) + 4g + (e&3), c = col.
    short8 a2[2];
#pragma unroll
    for (int t = 0; t < 2; ++t) {
#pragma unroll
        for (int e = 0; e < 8; ++e) {
            int j = 32 * t + 16 * (e >> 2) + 4 * g + (e & 3);
            float v = (col < OC) ? W2[j * OC + col] : 0.0f;
            a2[t][e] = bf16_of(v);
        }
    }

    // b2 bias per accY reg r: channel c = 4g + r (garbage rows harmless)
    f32x4 b2v;
#pragma unroll
    for (int r = 0; r < 4; ++r) b2v[r] = b2[(4 * g + r) & (OC - 1)];

    const float* xb = x + batch * LEN;
    float* ob = out + (size_t)batch * OUT_LEN * OC;

    for (int t8 = 0; t8 < TPW; ++t8) {
        const int p0 = (tile0 + t8) * 16;

        // B1 fragment: slot (g,e) = x[p0 + col + 8g + e] (index clamped; slots with
        // k>=16 multiply zero A1 rows so clamped garbage is harmless). Slot (2,0) = 1.0 for bias.
        short8 b1f;
#pragma unroll
        for (int e = 0; e < 8; ++e) {
            int idx = p0 + col + 8 * g + e;
            idx = idx < (LEN - 1) ? idx : (LEN - 1);
            b1f[e] = bf16_of(xb[idx]);
        }
        if (g == 2) b1f[0] = bf16_of(1.0f);

        // Layer 1: h^T tiles, D: col = position, row = j-row (4g + r) of tile T
        f32x4 acc[4] = {{0,0,0,0},{0,0,0,0},{0,0,0,0},{0,0,0,0}};
#pragma unroll
        for (int T = 0; T < 4; ++T)
            acc[T] = __builtin_amdgcn_mfma_f32_16x16x32_bf16(a1[T], b1f, acc[T], 0, 0, 0);

        // tanh + repack into B2 fragments (in-lane: slot (g,e) of tile t' <- tile 2t'+(e>>2), reg e&3)
        short8 hb[2];
#pragma unroll
        for (int T = 0; T < 4; ++T) {
#pragma unroll
            for (int r = 0; r < 4; ++r) {
                float h = acc[T][r];
                float e2 = __builtin_amdgcn_exp2f(h * 2.885390081777927f); // 2*log2(e)
                float t  = fmaf(-2.0f, __builtin_amdgcn_rcpf(e2 + 1.0f), 1.0f);
                hb[T >> 1][4 * (T & 1) + r] = bf16_of(t);
            }
        }

        // Layer 2: y^T = W2^T * tanh(h)^T, K=64 accumulated across 2 MFMAs
        f32x4 accY = b2v;
        accY = __builtin_amdgcn_mfma_f32_16x16x32_bf16(a2[0], hb[0], accY, 0, 0, 0);
        accY = __builtin_amdgcn_mfma_f32_16x16x32_bf16(a2[1], hb[1], accY, 0, 0, 0);

        // Store: lane (col = p, g<2) holds y[p][4g..4g+3] -> coalesced float4
        const int p = p0 + col;
        if (g < 2 && p < OUT_LEN) {
            *(f32x4*)(ob + (size_t)p * OC + 4 * g) = accY;
        }
    }
}

extern "C" void kernel_launch(void* const* d_in, const int* in_sizes, int n_in,
                              void* d_out, int out_size, void* d_ws, size_t ws_size,
                              hipStream_t stream) {
    const float* x  = (const float*)d_in[0];
    const float* W1 = (const float*)d_in[1];
    const float* b1 = (const float*)d_in[2];
    const float* W2 = (const float*)d_in[3];
    const float* b2 = (const float*)d_in[4];
    float* out = (float*)d_out;

    // 64 batches x 16 strips (of 32 tiles = 4 waves x 8 tiles) = 1024 blocks
    dim3 grid(BATCH * 16);
    conv_mlp_mfma<<<grid, 256, 0, stream>>>(x, W1, b1, W2, b2, out);
}

// Round 3
// 20.783 us; speedup vs baseline: 1.5317x; 1.0428x over previous
//
#include <hip/hip_runtime.h>
#include <hip/hip_bf16.h>

#define KS 16
#define HID 64
#define OC 8
#define LEN 8192
#define OUT_LEN (LEN - KS + 1)   // 8177
#define BATCH 64
#define TPW 4                    // tiles (of 16 positions) per wave
#define STRIPS 32                // blocks per batch; strip = 4 waves x 4 tiles = 16 tiles

typedef __attribute__((ext_vector_type(8))) short short8;   // 8 bf16
typedef __attribute__((ext_vector_type(4))) float f32x4;
typedef __attribute__((ext_vector_type(4), aligned(4))) float f32x4u; // 4B-aligned vec load

// HW round-to-nearest-even f32 -> bf16 (compiler emits v_cvt_pk_bf16_f32 for pairs)
static __device__ inline short bf16s(float f) {
    union { __hip_bfloat16 h; short s; } u;
    u.h = __float2bfloat16(f);
    return u.s;
}

__global__ __launch_bounds__(256, 4) void conv_mlp_mfma(
    const float* __restrict__ x, const float* __restrict__ W1,
    const float* __restrict__ b1, const float* __restrict__ W2,
    const float* __restrict__ b2, float* __restrict__ out)
{
    const int lane = threadIdx.x & 63;
    const int wave = threadIdx.x >> 6;
    const int col  = lane & 15;   // position within tile (B/D cols)
    const int g    = lane >> 4;   // 16-lane group

    const int batch = blockIdx.x >> 5;   // 32 strips per batch
    const int strip = blockIdx.x & 31;
    const int tile0 = strip * 16 + wave * TPW;

    // ---- A1 fragments: W1^T j-tiles (j = 16T + col), k-slot (g,e) -> k = 8g+e.
    //      k >= 16 zero-padded; slot (g=2,e=0) carries b1 (pairs with B1 slot = 1.0).
    short8 a1[4];
#pragma unroll
    for (int T = 0; T < 4; ++T) {
#pragma unroll
        for (int e = 0; e < 8; ++e) {
            float v = 0.0f;
            if (g < 2)                 v = W1[(8 * g + e) * HID + 16 * T + col];
            else if (g == 2 && e == 0) v = b1[16 * T + col];
            a1[T][e] = bf16s(v);
        }
    }

    // ---- A2 fragments: W2^T, slot (g,e) of K-tile t -> j = 32t + 16(e>>2) + 4g + (e&3), c = col.
    short8 a2[2];
#pragma unroll
    for (int t = 0; t < 2; ++t) {
#pragma unroll
        for (int e = 0; e < 8; ++e) {
            int j = 32 * t + 16 * (e >> 2) + 4 * g + (e & 3);
            float v = (col < OC) ? W2[j * OC + col] : 0.0f;
            a2[t][e] = bf16s(v);
        }
    }

    // b2 bias per accY reg r: channel c = 4g + r (g>=2 rows are discarded)
    f32x4 b2v;
#pragma unroll
    for (int r = 0; r < 4; ++r) b2v[r] = b2[(4 * g + r) & (OC - 1)];

    const float* xb = x + batch * LEN;
    float* ob = out + (size_t)batch * OUT_LEN * OC;

    for (int t8 = 0; t8 < TPW; ++t8) {
        const int p0 = (tile0 + t8) * 16;
        const int p  = p0 + col;

        // B1 fragment: slots (g,e) = x[p + 8g + e], contiguous in e -> 2 aligned
        // dwordx4 loads. g>=2 slots multiply zero A1 rows: skip loads, set 0.
        // Clamp base to LEN-8 (only affects slots feeding discarded positions).
        short8 b1f = {0, 0, 0, 0, 0, 0, 0, 0};
        if (g < 2) {
            int b0 = p + 8 * g;
            b0 = b0 > (LEN - 8) ? (LEN - 8) : b0;
            f32x4u lo = *(const f32x4u*)(xb + b0);
            f32x4u hi = *(const f32x4u*)(xb + b0 + 4);
#pragma unroll
            for (int e = 0; e < 4; ++e) b1f[e]     = bf16s(lo[e]);
#pragma unroll
            for (int e = 0; e < 4; ++e) b1f[4 + e] = bf16s(hi[e]);
        } else if (g == 2) {
            b1f[0] = (short)0x3F80;   // bf16(1.0) pairs with b1 row of A1
        }

        // Layer 1: h^T tiles; D: col = position, row j = 16T + 4g + r
        f32x4 acc[4] = {{0,0,0,0},{0,0,0,0},{0,0,0,0},{0,0,0,0}};
#pragma unroll
        for (int T = 0; T < 4; ++T)
            acc[T] = __builtin_amdgcn_mfma_f32_16x16x32_bf16(a1[T], b1f, acc[T], 0, 0, 0);

        // tanh + in-lane repack into B2 fragments: slot (g,e) of tile t' <- T = 2t'+(e>>2), r = e&3
        short8 hb[2];
#pragma unroll
        for (int T = 0; T < 4; ++T) {
#pragma unroll
            for (int r = 0; r < 4; ++r) {
                float h  = acc[T][r];
                float e2 = __builtin_amdgcn_exp2f(h * 2.885390081777927f); // 2*log2(e)
                float tn = fmaf(-2.0f, __builtin_amdgcn_rcpf(e2 + 1.0f), 1.0f);
                hb[T >> 1][4 * (T & 1) + r] = bf16s(tn);
            }
        }

        // Layer 2: y^T = W2^T * tanh(h)^T, K=64 over 2 MFMAs; D: col = position, row = channel 4g+r
        f32x4 accY = b2v;
        accY = __builtin_amdgcn_mfma_f32_16x16x32_bf16(a2[0], hb[0], accY, 0, 0, 0);
        accY = __builtin_amdgcn_mfma_f32_16x16x32_bf16(a2[1], hb[1], accY, 0, 0, 0);

        // Store: lane (col=p, g<2) holds y[p][4g..4g+3] -> coalesced float4
        if (g < 2 && p < OUT_LEN) {
            *(f32x4*)(ob + (size_t)p * OC + 4 * g) = accY;
        }
    }
}

extern "C" void kernel_launch(void* const* d_in, const int* in_sizes, int n_in,
                              void* d_out, int out_size, void* d_ws, size_t ws_size,
                              hipStream_t stream) {
    const float* x  = (const float*)d_in[0];
    const float* W1 = (const float*)d_in[1];
    const float* b1 = (const float*)d_in[2];
    const float* W2 = (const float*)d_in[3];
    const float* b2 = (const float*)d_in[4];
    float* out = (float*)d_out;

    dim3 grid(BATCH * STRIPS);   // 2048 blocks = 8 blocks/CU target
    conv_mlp_mfma<<<grid, 256, 0, stream>>>(x, W1, b1, W2, b2, out);
}

// Round 4
// 20.167 us; speedup vs baseline: 1.5785x; 1.0305x over previous
//
#include <hip/hip_runtime.h>
#include <hip/hip_bf16.h>

#define KS 16
#define HID 64
#define OC 8
#define LEN 8192
#define OUT_LEN (LEN - KS + 1)   // 8177
#define BATCH 64
#define TPW 8                    // tiles (of 16 positions) per wave
#define STRIPS 16                // strips per batch; strip = 4 waves x 8 tiles = 32 tiles

typedef __attribute__((ext_vector_type(8))) short short8;   // 8 bf16
typedef __attribute__((ext_vector_type(4))) float f32x4;
typedef __attribute__((ext_vector_type(4), aligned(4))) float f32x4u; // 4B-aligned vec load

// HW round-to-nearest-even f32 -> bf16 (pairs lower to v_cvt_pk_bf16_f32)
static __device__ inline short bf16s(float f) {
    union { __hip_bfloat16 h; short s; } u;
    u.h = __float2bfloat16(f);
    return u.s;
}

static __device__ inline void nt_store4(float* p, f32x4 v) {
    __builtin_nontemporal_store(v.x, p + 0);
    __builtin_nontemporal_store(v.y, p + 1);
    __builtin_nontemporal_store(v.z, p + 2);
    __builtin_nontemporal_store(v.w, p + 3);
}

__global__ __launch_bounds__(256, 4) void conv_mlp_mfma(
    const float* __restrict__ x, const float* __restrict__ W1,
    const float* __restrict__ b1, const float* __restrict__ W2,
    const float* __restrict__ b2, float* __restrict__ out)
{
    const int lane = threadIdx.x & 63;
    const int wave = threadIdx.x >> 6;
    const int col  = lane & 15;   // position within tile (B/D cols)
    const int g    = lane >> 4;   // 16-lane group

    const int batch = blockIdx.x >> 4;   // 16 strips per batch
    const int strip = blockIdx.x & 15;
    const int tile0 = strip * 32 + wave * TPW;

    // ---- A1 fragments: W1^T j-tiles (j = 16T + col), k-slot (g,e) -> k = 8g+e.
    //      k >= 16 zero-padded; slot (g=2,e=0) carries b1 (pairs with B1 slot = 1.0).
    short8 a1[4];
#pragma unroll
    for (int T = 0; T < 4; ++T) {
#pragma unroll
        for (int e = 0; e < 8; ++e) {
            float v = 0.0f;
            if (g < 2)                 v = W1[(8 * g + e) * HID + 16 * T + col];
            else if (g == 2 && e == 0) v = b1[16 * T + col];
            a1[T][e] = bf16s(v);
        }
    }

    // ---- A2 fragments: W2^T, slot (g,e) of K-tile t -> j = 32t + 16(e>>2) + 4g + (e&3), c = col.
    short8 a2[2];
#pragma unroll
    for (int t = 0; t < 2; ++t) {
#pragma unroll
        for (int e = 0; e < 8; ++e) {
            int j = 32 * t + 16 * (e >> 2) + 4 * g + (e & 3);
            float v = (col < OC) ? W2[j * OC + col] : 0.0f;
            a2[t][e] = bf16s(v);
        }
    }

    // b2 bias per accY reg r: channel c = 4g + r (g>=2 rows discarded)
    f32x4 b2v;
#pragma unroll
    for (int r = 0; r < 4; ++r) b2v[r] = b2[(4 * g + r) & (OC - 1)];

    const float* xb = x + batch * LEN;
    float* ob = out + (size_t)batch * OUT_LEN * OC;

    // Per-tile load base (clamped; clamp only engages for lanes whose results
    // are masked anyway). Unconditional loads keep the prefetch rotation branch-free.
    const int boff = col + 8 * (g & 1);   // g>=2 mirrors g&1; values discarded via select

    // Prefetch tile 0
    int nb = tile0 * 16 + boff;
    nb = nb > (LEN - 8) ? (LEN - 8) : nb;
    f32x4 nlo = *(const f32x4u*)(xb + nb);
    f32x4 nhi = *(const f32x4u*)(xb + nb + 4);

#pragma unroll
    for (int t8 = 0; t8 < TPW; ++t8) {
        const int p0 = (tile0 + t8) * 16;
        const int p  = p0 + col;

        f32x4 clo = nlo, chi = nhi;
        if (t8 + 1 < TPW) {
            int b0 = (p0 + 16) + boff;
            b0 = b0 > (LEN - 8) ? (LEN - 8) : b0;
            nlo = *(const f32x4u*)(xb + b0);
            nhi = *(const f32x4u*)(xb + b0 + 4);
        }

        // B1 fragment: slots (g,e) = x[p + 8g + e] for g<2; g==2 slot0 = 1.0 (bias); rest 0.
        short8 b1f;
#pragma unroll
        for (int e = 0; e < 4; ++e) b1f[e]     = bf16s(clo[e]);
#pragma unroll
        for (int e = 0; e < 4; ++e) b1f[4 + e] = bf16s(chi[e]);
        if (g >= 2) {
            short8 z = {0, 0, 0, 0, 0, 0, 0, 0};
            if (g == 2) z[0] = (short)0x3F80;   // bf16(1.0) pairs with b1 row of A1
            b1f = z;
        }

        // Layer 1: h^T tiles; D: col = position, row j = 16T + 4g + r
        f32x4 acc[4] = {{0,0,0,0},{0,0,0,0},{0,0,0,0},{0,0,0,0}};
#pragma unroll
        for (int T = 0; T < 4; ++T)
            acc[T] = __builtin_amdgcn_mfma_f32_16x16x32_bf16(a1[T], b1f, acc[T], 0, 0, 0);

        // tanh + in-lane repack into B2 fragments: slot (g,e) of tile t' <- T = 2t'+(e>>2), r = e&3
        short8 hb[2];
#pragma unroll
        for (int T = 0; T < 4; ++T) {
#pragma unroll
            for (int r = 0; r < 4; ++r) {
                float h  = acc[T][r];
                float e2 = __builtin_amdgcn_exp2f(h * 2.885390081777927f); // 2*log2(e)
                float tn = fmaf(-2.0f, __builtin_amdgcn_rcpf(e2 + 1.0f), 1.0f);
                hb[T >> 1][4 * (T & 1) + r] = bf16s(tn);
            }
        }

        // Layer 2: y^T, K=64 over 2 MFMAs; D: col = position, row = channel 4g+r
        f32x4 accY = b2v;
        accY = __builtin_amdgcn_mfma_f32_16x16x32_bf16(a2[0], hb[0], accY, 0, 0, 0);
        accY = __builtin_amdgcn_mfma_f32_16x16x32_bf16(a2[1], hb[1], accY, 0, 0, 0);

        // Store: lane (col=p, g<2) holds y[p][4g..4g+3]; nontemporal (out never re-read)
        if (g < 2 && p < OUT_LEN) {
            nt_store4(ob + (size_t)p * OC + 4 * g, accY);
        }
    }
}

extern "C" void kernel_launch(void* const* d_in, const int* in_sizes, int n_in,
                              void* d_out, int out_size, void* d_ws, size_t ws_size,
                              hipStream_t stream) {
    const float* x  = (const float*)d_in[0];
    const float* W1 = (const float*)d_in[1];
    const float* b1 = (const float*)d_in[2];
    const float* W2 = (const float*)d_in[3];
    const float* b2 = (const float*)d_in[4];
    float* out = (float*)d_out;

    dim3 grid(BATCH * STRIPS);   // 1024 blocks = 4 blocks/CU
    conv_mlp_mfma<<<grid, 256, 0, stream>>>(x, W1, b1, W2, b2, out);
}